// Round 6
// baseline (138.794 us; speedup 1.0000x reference)
//
#include <hip/hip_runtime.h>

#define NB 8
#define NS 4096
#define ND 768

// packed-f4 layout inside wpack / LDS (units of float4):
//   [0,1536)    panel weights  : o*192 + i
//   [1536,4608) dialog weights : 1536 + o*384 + i  (+192 = parent half)
//   [4608,6144) char weights   : 4608 + o*384 + i  (+192 = parent half)
//   [6144,6336) lng | [6336,6528) lnb | [6528,6720) this block's sprj row
#define WPACK_F4 6528
#define LDS_F4   6720

typedef float4 f4;

static __device__ __forceinline__ f4 ld4(const float* __restrict__ p, int i) {
    return ((const f4*)p)[i];
}

static __device__ __forceinline__ void dot4(float& acc, const f4& a, const f4& w) {
    acc = fmaf(a.x, w.x, acc);
    acc = fmaf(a.y, w.y, acc);
    acc = fmaf(a.z, w.z, acc);
    acc = fmaf(a.w, w.w, acc);
}

// ---------------------------------------------------------------------------
// Kernel 1 (lp_setup), 16 blocks x 1024 threads — replaces memset + lp_pre +
// lp_parent (3 dispatches -> part of 1):
//   blocks 0..7  : batch b = bx. Build parent table in LDS (scatter-max over
//                  4096 tokens, 4/thread), write to global; compute style row
//                  into registers (all waves, redundant, L2-hot) and write it
//                  once; then 64 parent-panel feats (16 waves x 4 rounds)
//                  using the LDS table + register style row.
//   blocks 8..15 : pack head weights + ln params into wpack (contiguous).
// ---------------------------------------------------------------------------
__global__ __launch_bounds__(1024) void lp_setup(
    const int* __restrict__ et, const int* __restrict__ ei, const int* __restrict__ ppi,
    const float* __restrict__ sv, const float* __restrict__ sw,
    const float* __restrict__ sb,
    const float* __restrict__ temb, const float* __restrict__ iemb,
    const float* __restrict__ pemb,
    const float* __restrict__ lng, const float* __restrict__ lnb,
    const float* __restrict__ pw, const float* __restrict__ dw,
    const float* __restrict__ cw,
    int* __restrict__ table, float* __restrict__ sprj,
    float* __restrict__ wpack, float* __restrict__ pfeat)
{
    const int bx = blockIdx.x;
    const int tid = threadIdx.x;

    if (bx < NB) {
        __shared__ int ltab[64];
        const int lane = tid & 63;
        const int wid = tid >> 6;              // 0..15
        if (tid < 64) ltab[tid] = -1;
        __syncthreads();

        // scatter-max parent table for batch bx (4096 tokens, 4/thread)
        const int base = bx * NS;
        #pragma unroll
        for (int r = 0; r < 4; ++r) {
            int s = r * 1024 + tid;
            int tok = base + s;
            if (et[tok] == 1) atomicMax(&ltab[ei[tok]], s);
        }
        __syncthreads();
        if (tid < 64) table[bx * 64 + tid] = ltab[tid];

        // style row into registers (every wave; sw/sb are L2-hot broadcast)
        const float sv0 = sv[bx*4+0], sv1 = sv[bx*4+1], sv2 = sv[bx*4+2], sv3 = sv[bx*4+3];
        f4 sp[3];
        #pragma unroll
        for (int g = 0; g < 3; ++g) {
            int i = g*64 + lane;
            f4 w0 = ld4(sw, i), w1 = ld4(sw, 192+i), w2 = ld4(sw, 384+i), w3 = ld4(sw, 576+i);
            f4 bb = ld4(sb, i);
            f4 r;
            r.x = bb.x + sv0*w0.x + sv1*w1.x + sv2*w2.x + sv3*w3.x;
            r.y = bb.y + sv0*w0.y + sv1*w1.y + sv2*w2.y + sv3*w3.y;
            r.z = bb.z + sv0*w0.z + sv1*w1.z + sv2*w2.z + sv3*w3.z;
            r.w = bb.w + sv0*w0.w + sv1*w1.w + sv2*w2.w + sv3*w3.w;
            sp[g] = r;
            if (wid == 0) ((f4*)(sprj + bx*ND))[i] = r;   // once to global
        }

        // parent panel feats: 64 slots, 16 waves x 4 rounds, LDS table
        for (int r = 0; r < 4; ++r) {
            const int slot = r * 16 + wid;                 // 0..63, wave-uniform
            const int pp = ltab[slot];
            if (pp < 0) continue;
            const int ptok = base + pp;
            const int pei = ei[ptok], pppi = ppi[ptok];
            const float* ie = iemb + pei * ND;
            const float* pe = pemb + pppi * ND;

            f4 x[3]; float s1 = 0.f, sq = 0.f;
            #pragma unroll
            for (int g = 0; g < 3; ++g) {
                int i = g*64 + lane;
                f4 a = ld4(temb + ND, i), c = ld4(ie, i), d = ld4(pe, i);
                f4 v;
                v.x = a.x + c.x + d.x + sp[g].x;
                v.y = a.y + c.y + d.y + sp[g].y;
                v.z = a.z + c.z + d.z + sp[g].z;
                v.w = a.w + c.w + d.w + sp[g].w;
                x[g] = v;
                s1 += v.x + v.y + v.z + v.w;
                sq = fmaf(v.x, v.x, sq);
                sq = fmaf(v.y, v.y, sq);
                sq = fmaf(v.z, v.z, sq);
                sq = fmaf(v.w, v.w, sq);
            }
            #pragma unroll
            for (int k = 32; k >= 1; k >>= 1) {
                s1 += __shfl_xor(s1, k, 64);
                sq += __shfl_xor(sq, k, 64);
            }
            float mu = s1 * (1.f/ND);
            float rs = rsqrtf(sq * (1.f/ND) - mu * mu + 1e-5f);
            float c0 = -mu * rs;
            float* dst = pfeat + (size_t)(bx * 64 + slot) * ND;
            #pragma unroll
            for (int g = 0; g < 3; ++g) {
                int i = g*64 + lane;
                f4 gg = ld4(lng, i), bb = ld4(lnb, i);
                f4 v = x[g], xn;
                xn.x = fmaf(v.x, rs, c0); v.x = fmaf(xn.x, gg.x, bb.x);
                xn.y = fmaf(v.y, rs, c0); v.y = fmaf(xn.y, gg.y, bb.y);
                xn.z = fmaf(v.z, rs, c0); v.z = fmaf(xn.z, gg.z, bb.z);
                xn.w = fmaf(v.w, rs, c0); v.w = fmaf(xn.w, gg.w, bb.w);
                ((f4*)dst)[i] = v;
            }
        }
    } else {
        // pack head weights + ln params (8 blocks x 1024 >= 6528 f4)
        const int q = (bx - NB) * 1024 + tid;
        if (q >= WPACK_F4) return;
        f4 r;
        if (q < 1536) {                                  // panel: 8 x 192
            int o = q / 192, i = q - o * 192, d0 = 4 * i;
            r.x = pw[(d0+0)*8 + o];
            r.y = pw[(d0+1)*8 + o];
            r.z = pw[(d0+2)*8 + o];
            r.w = pw[(d0+3)*8 + o];
        } else if (q < 4608) {                           // dialog: 8 x 384
            int u = q - 1536;
            int o = u / 384, i = u - o * 384;
            int d0 = (i < 192) ? 4*i : 768 + 4*(i - 192);
            r.x = dw[(d0+0)*8 + o];
            r.y = dw[(d0+1)*8 + o];
            r.z = dw[(d0+2)*8 + o];
            r.w = dw[(d0+3)*8 + o];
        } else if (q < 6144) {                           // char: 4 x 384
            int u = q - 4608;
            int o = u / 384, i = u - o * 384;
            int d0 = (i < 192) ? 4*i : 768 + 4*(i - 192);
            r.x = cw[(d0+0)*4 + o];
            r.y = cw[(d0+1)*4 + o];
            r.z = cw[(d0+2)*4 + o];
            r.w = cw[(d0+3)*4 + o];
        } else if (q < 6336) {                           // lng
            r = ld4(lng, q - 6144);
        } else {                                         // lnb
            r = ld4(lnb, q - 6336);
        }
        ((f4*)wpack)[q] = r;
    }
}

// ---------------------------------------------------------------------------
// Kernel 2 (lp_main): PERSISTENT. 256 blocks x 1024 threads = 1 block/CU
// (107 KB LDS). Stage all weights ONCE, then each wave loops over 8 tokens
// with no barrier in the loop. Parent feats loaded into xp[3] EARLY (right
// after own-feat gathers) so their latency hides under the stats butterfly
// and normalize instead of stalling head phase B. LDS cap = 16 waves/CU
// allows up to 128 VGPR, so the +12 regs are free.
// ---------------------------------------------------------------------------
__global__ __launch_bounds__(1024) void lp_main(
    const int* __restrict__ et, const int* __restrict__ ei, const int* __restrict__ ppi,
    const float* __restrict__ temb, const float* __restrict__ iemb,
    const float* __restrict__ pemb,
    const float* __restrict__ pb, const float* __restrict__ db,
    const float* __restrict__ cb,
    const int* __restrict__ table, const float* __restrict__ sprj,
    const float* __restrict__ wpack, const float* __restrict__ pfeat,
    float* __restrict__ out)
{
    __shared__ f4 S[LDS_F4];                 // 107,520 B -> 1 block/CU
    const int tid = threadIdx.x;
    const int lane = tid & 63;
    const int wid = tid >> 6;                // 0..15
    const int bx = blockIdx.x;               // 0..255
    const int b = bx >> 5;                   // 32 blocks per batch

    // ---- stage weights + ln + style row into LDS once ----
    for (int i = tid; i < WPACK_F4; i += 1024) S[i] = ((const f4*)wpack)[i];
    if (tid < 192) S[WPACK_F4 + tid] = ((const f4*)(sprj + b * ND))[tid];
    __syncthreads();

    // ---- prefetch scalars for first token ----
    int t = bx * 128 + wid;
    int type = et[t], my_ei = ei[t], my_ppi = ppi[t];

    for (int r = 0; r < 8; ++r) {
        // prefetch next token's scalars (breaks index->gather dependency)
        const int tn = t + 16;
        int type_n = 0, ei_n = 0, ppi_n = 0;
        if (r < 7) { type_n = et[tn]; ei_n = ei[tn]; ppi_n = ppi[tn]; }

        f4 z4; z4.x = 0.f; z4.y = 0.f; z4.z = 0.f; z4.w = 0.f;
        f4 po0 = z4, po1 = z4, dq0 = z4, dq1 = z4, cq0 = z4;

        if (type != 0) {
            int pp = -1;
            if (type != 1) pp = table[b * 64 + my_ppi];   // issue early

            const float* te = temb + type * ND;
            const float* ie = iemb + my_ei * ND;
            const float* pe = pemb + my_ppi * ND;

            // --- own feats: embedding sum + style proj, single-pass stats ---
            f4 x[3];
            float s1 = 0.f, sq = 0.f;
            #pragma unroll
            for (int g = 0; g < 3; ++g) {
                int i = g * 64 + lane;
                f4 a = ld4(te, i), c = ld4(ie, i), d = ld4(pe, i);
                f4 s = S[WPACK_F4 + i];
                f4 v;
                v.x = a.x + c.x + d.x + s.x;
                v.y = a.y + c.y + d.y + s.y;
                v.z = a.z + c.z + d.z + s.z;
                v.w = a.w + c.w + d.w + s.w;
                x[g] = v;
                s1 += v.x + v.y + v.z + v.w;
                sq = fmaf(v.x, v.x, sq);
                sq = fmaf(v.y, v.y, sq);
                sq = fmaf(v.z, v.z, sq);
                sq = fmaf(v.w, v.w, sq);
            }

            // --- early parent-feat load: latency hides under butterfly ---
            f4 xp[3];
            const bool child = (type != 1) && (pp >= 0);
            if (child) {
                const float* pfr = pfeat + (size_t)(b * 64 + my_ppi) * ND;
                #pragma unroll
                for (int g = 0; g < 3; ++g)
                    xp[g] = ld4(pfr, g * 64 + lane);
            }

            #pragma unroll
            for (int k = 32; k >= 1; k >>= 1) {
                s1 += __shfl_xor(s1, k, 64);
                sq += __shfl_xor(sq, k, 64);
            }
            float mu = s1 * (1.f / ND);
            float rs = rsqrtf(sq * (1.f / ND) - mu * mu + 1e-5f);
            float c0 = -mu * rs;
            #pragma unroll
            for (int g = 0; g < 3; ++g) {
                int i = g * 64 + lane;
                f4 gg = S[6144 + i], bb = S[6336 + i];
                f4 v = x[g], xn;
                xn.x = fmaf(v.x, rs, c0); v.x = fmaf(xn.x, gg.x, bb.x);
                xn.y = fmaf(v.y, rs, c0); v.y = fmaf(xn.y, gg.y, bb.y);
                xn.z = fmaf(v.z, rs, c0); v.z = fmaf(xn.z, gg.z, bb.z);
                xn.w = fmaf(v.w, rs, c0); v.w = fmaf(xn.w, gg.w, bb.w);
                x[g] = v;
            }

            if (type == 1) {
                float acc[8];
                #pragma unroll
                for (int o = 0; o < 8; ++o) acc[o] = 0.f;
                #pragma unroll
                for (int g = 0; g < 3; ++g) {
                    int i = g * 64 + lane;
                    #pragma unroll
                    for (int o = 0; o < 8; ++o)
                        dot4(acc[o], x[g], S[o * 192 + i]);
                }
                #pragma unroll
                for (int k = 32; k >= 1; k >>= 1) {
                    #pragma unroll
                    for (int o = 0; o < 8; ++o)
                        acc[o] += __shfl_xor(acc[o], k, 64);
                }
                po0.x = acc[0] + pb[0]; po0.y = acc[1] + pb[1];
                po0.z = acc[2] + pb[2]; po0.w = acc[3] + pb[3];
                po1.x = acc[4] + pb[4]; po1.y = acc[5] + pb[5];
                po1.z = acc[6] + pb[6]; po1.w = acc[7] + pb[7];
            } else if (child) {
                if (type == 2) {
                    float acc[8];
                    #pragma unroll
                    for (int o = 0; o < 8; ++o) acc[o] = 0.f;
                    #pragma unroll
                    for (int g = 0; g < 3; ++g) {
                        int i = g * 64 + lane;
                        #pragma unroll
                        for (int o = 0; o < 8; ++o) {
                            dot4(acc[o], x[g],  S[1536 + o * 384 + i]);
                            dot4(acc[o], xp[g], S[1536 + o * 384 + 192 + i]);
                        }
                    }
                    #pragma unroll
                    for (int k = 32; k >= 1; k >>= 1) {
                        #pragma unroll
                        for (int o = 0; o < 8; ++o)
                            acc[o] += __shfl_xor(acc[o], k, 64);
                    }
                    dq0.x = acc[0] + db[0]; dq0.y = acc[1] + db[1];
                    dq0.z = acc[2] + db[2]; dq0.w = acc[3] + db[3];
                    dq1.x = acc[4] + db[4]; dq1.y = acc[5] + db[5];
                    dq1.z = acc[6] + db[6]; dq1.w = acc[7] + db[7];
                } else {
                    float acc[4];
                    #pragma unroll
                    for (int o = 0; o < 4; ++o) acc[o] = 0.f;
                    #pragma unroll
                    for (int g = 0; g < 3; ++g) {
                        int i = g * 64 + lane;
                        #pragma unroll
                        for (int o = 0; o < 4; ++o) {
                            dot4(acc[o], x[g],  S[4608 + o * 384 + i]);
                            dot4(acc[o], xp[g], S[4608 + o * 384 + 192 + i]);
                        }
                    }
                    #pragma unroll
                    for (int k = 32; k >= 1; k >>= 1) {
                        #pragma unroll
                        for (int o = 0; o < 4; ++o)
                            acc[o] += __shfl_xor(acc[o], k, 64);
                    }
                    cq0.x = acc[0] + cb[0]; cq0.y = acc[1] + cb[1];
                    cq0.z = acc[2] + cb[2]; cq0.w = acc[3] + cb[3];
                }
            }
        }

        // every wave writes its 20 outputs (zeros for masked / type-0 tokens)
        if (lane == 0) {
            f4* op = (f4*)(out + (size_t)t * 8);
            op[0] = po0; op[1] = po1;
            f4* od = (f4*)(out + (size_t)NB * NS * 8 + (size_t)t * 8);
            od[0] = dq0; od[1] = dq1;
            ((f4*)(out + (size_t)NB * NS * 16 + (size_t)t * 4))[0] = cq0;
        }

        t = tn; type = type_n; my_ei = ei_n; my_ppi = ppi_n;
    }
}

extern "C" void kernel_launch(void* const* d_in, const int* in_sizes, int n_in,
                              void* d_out, int out_size, void* d_ws, size_t ws_size,
                              hipStream_t stream) {
    const int* et  = (const int*)d_in[0];
    const int* ei  = (const int*)d_in[1];
    const int* ppi = (const int*)d_in[2];
    const float* sv   = (const float*)d_in[3];
    const float* temb = (const float*)d_in[4];
    const float* iemb = (const float*)d_in[5];
    const float* pemb = (const float*)d_in[6];
    const float* sw   = (const float*)d_in[7];
    const float* sb   = (const float*)d_in[8];
    const float* lng  = (const float*)d_in[9];
    const float* lnb  = (const float*)d_in[10];
    const float* pw   = (const float*)d_in[11];
    const float* pb   = (const float*)d_in[12];
    const float* dw   = (const float*)d_in[13];
    const float* db   = (const float*)d_in[14];
    const float* cw   = (const float*)d_in[15];
    const float* cbp  = (const float*)d_in[16];
    float* out = (float*)d_out;

    // ws layout: [0,2KB) table | [4KB,28KB) sproj | [32KB,+104448B) wpack
    //            | then pfeat (512x768 f32 = 1.5MB)
    int*   table = (int*)d_ws;
    float* sprj  = (float*)((char*)d_ws + 4096);
    float* wpack = (float*)((char*)d_ws + 32768);
    float* pfeat = (float*)((char*)d_ws + 32768 + WPACK_F4 * 16);

    lp_setup<<<16, 1024, 0, stream>>>(et, ei, ppi, sv, sw, sb, temb, iemb, pemb,
                                      lng, lnb, pw, dw, cw,
                                      table, sprj, wpack, pfeat);
    lp_main<<<256, 1024, 0, stream>>>(et, ei, ppi, temb, iemb, pemb,
                                      pb, db, cbp,
                                      table, sprj, wpack, pfeat, out);
}